// Round 1
// baseline (9102.172 us; speedup 1.0000x reference)
//
#include <hip/hip_runtime.h>
#include <hip/hip_bf16.h>
#include <math.h>

// ---------------- problem constants ----------------
#define S 1024
#define H 2048
#define NH 16
#define HD 128
#define E 16
#define TOPK 4
#define IM 1408
#define IS 5632
#define EPS 1e-6f
#define THETA 1000000.0f

// ---------------- tiled f32 GEMM: C[M,N] = A[M,K] @ B[K,N] (+bias +add) ----
// A row-major [M,K], B row-major [K,N]. K must be a multiple of 16.
#define BM 64
#define BN 64
#define BK 16

__global__ __launch_bounds__(256)
void gemm_f32(const float* __restrict__ A, const float* __restrict__ B,
              const float* __restrict__ bias, const float* __restrict__ add,
              float* __restrict__ C, int M, int N, int K) {
    __shared__ float As[BK][BM + 4];
    __shared__ float Bs[BK][BN + 4];
    const int tid = threadIdx.x;
    const int m0 = blockIdx.y * BM, n0 = blockIdx.x * BN;
    const int tx = tid & 15, ty = tid >> 4;
    float c[4][4] = {};
    for (int k0 = 0; k0 < K; k0 += BK) {
        for (int i = tid; i < BM * BK; i += 256) {
            int m = i / BK, kk = i % BK;
            int gm = m0 + m;
            As[kk][m] = (gm < M) ? A[(size_t)gm * K + k0 + kk] : 0.f;
        }
        for (int i = tid; i < BK * BN; i += 256) {
            int kk = i / BN, n = i % BN;
            int gn = n0 + n;
            Bs[kk][n] = (gn < N) ? B[(size_t)(k0 + kk) * N + gn] : 0.f;
        }
        __syncthreads();
#pragma unroll
        for (int kk = 0; kk < BK; ++kk) {
            float a[4], b[4];
#pragma unroll
            for (int i = 0; i < 4; ++i) a[i] = As[kk][ty * 4 + i];
#pragma unroll
            for (int j = 0; j < 4; ++j) b[j] = Bs[kk][tx * 4 + j];
#pragma unroll
            for (int i = 0; i < 4; ++i)
#pragma unroll
                for (int j = 0; j < 4; ++j) c[i][j] += a[i] * b[j];
        }
        __syncthreads();
    }
#pragma unroll
    for (int i = 0; i < 4; ++i) {
        int gm = m0 + ty * 4 + i;
        if (gm >= M) continue;
#pragma unroll
        for (int j = 0; j < 4; ++j) {
            int gn = n0 + tx * 4 + j;
            if (gn >= N) continue;
            float val = c[i][j];
            if (bias) val += bias[gn];
            if (add) val += add[(size_t)gm * N + gn];
            C[(size_t)gm * N + gn] = val;
        }
    }
}

// ---------------- RMSNorm: one block per token ----------------
__global__ __launch_bounds__(256)
void rmsnorm_kernel(const float* __restrict__ x, const float* __restrict__ w,
                    float* __restrict__ o) {
    const int s = blockIdx.x, tid = threadIdx.x;
    __shared__ float red[256];
    const float* xr = x + (size_t)s * H;
    float ss = 0.f;
    for (int d = tid; d < H; d += 256) { float t = xr[d]; ss += t * t; }
    red[tid] = ss; __syncthreads();
    for (int st = 128; st > 0; st >>= 1) {
        if (tid < st) red[tid] += red[tid + st];
        __syncthreads();
    }
    const float r = rsqrtf(red[0] / (float)H + EPS);
    float* orow = o + (size_t)s * H;
    for (int d = tid; d < H; d += 256) orow[d] = xr[d] * r * w[d];
}

// ---------------- RoPE (neox, in place): grid (S, NH), 64 threads ----------
__global__ __launch_bounds__(64)
void rope_kernel(float* __restrict__ x, const int* __restrict__ positions) {
    const int s = blockIdx.x, h = blockIdx.y, t = threadIdx.x;  // t in [0,64)
    const float pos = (float)positions[s];
    const float inv_freq = powf(THETA, -(float)t / 64.0f);
    const float ang = pos * inv_freq;
    float sn, cs;
    sincosf(ang, &sn, &cs);
    const size_t base = (size_t)s * (NH * HD) + (size_t)h * HD;
    const float x1 = x[base + t];
    const float x2 = x[base + t + 64];
    x[base + t]      = x1 * cs - x2 * sn;
    x[base + t + 64] = x2 * cs + x1 * sn;
}

// ---------------- causal attention, naive: block = (query i, head h) -------
__global__ __launch_bounds__(256)
void attn_kernel(const float* __restrict__ q, const float* __restrict__ k,
                 const float* __restrict__ v, float* __restrict__ out) {
    const int i = blockIdx.x, h = blockIdx.y, tid = threadIdx.x;
    __shared__ float qs[HD];
    __shared__ float sc[S];
    __shared__ float red[256];
    const float scale = 0.08838834764831845f;  // 1/sqrt(128)
    for (int d = tid; d < HD; d += 256) qs[d] = q[(size_t)i * (NH * HD) + h * HD + d];
    __syncthreads();
    const int L = i + 1;
    for (int j = tid; j < L; j += 256) {
        const float* kr = k + (size_t)j * (NH * HD) + h * HD;
        float acc = 0.f;
#pragma unroll 16
        for (int d = 0; d < HD; ++d) acc += qs[d] * kr[d];
        sc[j] = acc * scale;
    }
    __syncthreads();
    // max
    float mx = -1e30f;
    for (int j = tid; j < L; j += 256) mx = fmaxf(mx, sc[j]);
    red[tid] = mx; __syncthreads();
    for (int st = 128; st > 0; st >>= 1) {
        if (tid < st) red[tid] = fmaxf(red[tid], red[tid + st]);
        __syncthreads();
    }
    mx = red[0]; __syncthreads();
    // exp + sum
    float sum = 0.f;
    for (int j = tid; j < L; j += 256) { float e = expf(sc[j] - mx); sc[j] = e; sum += e; }
    red[tid] = sum; __syncthreads();
    for (int st = 128; st > 0; st >>= 1) {
        if (tid < st) red[tid] += red[tid + st];
        __syncthreads();
    }
    const float inv = 1.0f / red[0];
    __syncthreads();
    // PV: 128 dims, 2 j-halves
    const int d = tid & 127, half = tid >> 7;
    float acc = 0.f;
    for (int j = half; j < L; j += 2) acc += sc[j] * v[(size_t)j * (NH * HD) + h * HD + d];
    red[tid] = acc; __syncthreads();
    if (half == 0)
        out[(size_t)i * (NH * HD) + h * HD + d] = (red[tid] + red[tid + 128]) * inv;
}

// ---------------- silu(g) * u elementwise ----------------
__global__ __launch_bounds__(256)
void silu_mul_kernel(const float* __restrict__ g, const float* __restrict__ u,
                     float* __restrict__ t, size_t n) {
    size_t i = (size_t)blockIdx.x * 256 + threadIdx.x;
    if (i < n) { float x = g[i]; t[i] = x / (1.f + expf(-x)) * u[i]; }
}

// ---------------- sigmoid(h2 . wsg) * shared_row ----------------
__global__ __launch_bounds__(256)
void gate_scale_kernel(const float* __restrict__ h2, const float* __restrict__ wsg,
                       float* __restrict__ shared_out) {
    const int s = blockIdx.x, tid = threadIdx.x;
    __shared__ float red[256];
    float acc = 0.f;
    for (int d = tid; d < H; d += 256) acc += h2[(size_t)s * H + d] * wsg[d];
    red[tid] = acc; __syncthreads();
    for (int st = 128; st > 0; st >>= 1) {
        if (tid < st) red[tid] += red[tid + st];
        __syncthreads();
    }
    const float gate = 1.f / (1.f + expf(-red[0]));
    for (int d = tid; d < H; d += 256) shared_out[(size_t)s * H + d] *= gate;
}

// ---------------- router: softmax + top-4 + renorm, 1 thread per token -----
__global__ __launch_bounds__(256)
void router_top4_kernel(const float* __restrict__ logits, int* __restrict__ tk_ids,
                        float* __restrict__ tk_w) {
    const int s = blockIdx.x * 256 + threadIdx.x;
    if (s >= S) return;
    float l[E];
    float mx = -1e30f;
    for (int e = 0; e < E; ++e) { l[e] = logits[s * E + e]; mx = fmaxf(mx, l[e]); }
    float sum = 0.f;
    for (int e = 0; e < E; ++e) { l[e] = expf(l[e] - mx); sum += l[e]; }
    float wsum = 0.f;
    for (int kk = 0; kk < TOPK; ++kk) {
        int best = 0; float bv = -1e30f;
        for (int e = 0; e < E; ++e) if (l[e] > bv) { bv = l[e]; best = e; }
        tk_ids[s * TOPK + kk] = best;
        float w = bv / sum;
        tk_w[s * TOPK + kk] = w;
        wsum += w;
        l[best] = -1e30f;
    }
    const float inv = 1.f / wsum;
    for (int kk = 0; kk < TOPK; ++kk) tk_w[s * TOPK + kk] *= inv;
}

__global__ void count_pairs_kernel(const int* __restrict__ tk_ids, int* __restrict__ counts) {
    const int s = blockIdx.x * 256 + threadIdx.x;
    if (s >= S) return;
    for (int kk = 0; kk < TOPK; ++kk) atomicAdd(&counts[tk_ids[s * TOPK + kk]], 1);
}

__global__ void scan_offsets_kernel(const int* __restrict__ counts, int* __restrict__ offs) {
    if (threadIdx.x == 0) {
        int acc = 0;
        for (int e = 0; e < E; ++e) { offs[e] = acc; acc += counts[e]; }
    }
}

__global__ void place_pairs_kernel(const int* __restrict__ tk_ids, const float* __restrict__ tk_w,
                                   const int* __restrict__ offs, int* __restrict__ fill,
                                   int* __restrict__ tok_list, float* __restrict__ pw) {
    const int s = blockIdx.x * 256 + threadIdx.x;
    if (s >= S) return;
    for (int kk = 0; kk < TOPK; ++kk) {
        int e = tk_ids[s * TOPK + kk];
        int slot = atomicAdd(&fill[e], 1);
        tok_list[offs[e] + slot] = s;
        pw[offs[e] + slot] = tk_w[s * TOPK + kk];
    }
}

// ---------------- expert gate/up (grouped GEMM + silu*mul fused) -----------
// grid: (IM/BN, E). Loops over this expert's token tiles.
__global__ __launch_bounds__(256)
void expert_gateup_kernel(const float* __restrict__ h2, const float* __restrict__ wg_all,
                          const float* __restrict__ wu_all, const int* __restrict__ counts,
                          const int* __restrict__ offs, const int* __restrict__ tok_list,
                          float* __restrict__ t_out) {
    const int e = blockIdx.y;
    const int cnt = counts[e];
    if (cnt == 0) return;
    const int base = offs[e];
    const float* wg = wg_all + (size_t)e * H * IM;
    const float* wu = wu_all + (size_t)e * H * IM;
    const int n0 = blockIdx.x * BN;
    __shared__ float As[BK][BM + 4];
    __shared__ float Bg[BK][BN + 4];
    __shared__ float Bu[BK][BN + 4];
    __shared__ int toks[BM];
    const int tid = threadIdx.x, tx = tid & 15, ty = tid >> 4;
    for (int m0 = 0; m0 < cnt; m0 += BM) {
        if (tid < BM) toks[tid] = (m0 + tid < cnt) ? tok_list[base + m0 + tid] : 0;
        __syncthreads();
        float cg[4][4] = {}, cu[4][4] = {};
        for (int k0 = 0; k0 < H; k0 += BK) {
            for (int i = tid; i < BM * BK; i += 256) {
                int m = i / BK, kk = i % BK;
                As[kk][m] = (m0 + m < cnt) ? h2[(size_t)toks[m] * H + k0 + kk] : 0.f;
            }
            for (int i = tid; i < BK * BN; i += 256) {
                int kk = i / BN, n = i % BN;
                Bg[kk][n] = wg[(size_t)(k0 + kk) * IM + n0 + n];
                Bu[kk][n] = wu[(size_t)(k0 + kk) * IM + n0 + n];
            }
            __syncthreads();
#pragma unroll
            for (int kk = 0; kk < BK; ++kk) {
                float a[4], bg[4], bu[4];
#pragma unroll
                for (int i = 0; i < 4; ++i) a[i] = As[kk][ty * 4 + i];
#pragma unroll
                for (int j = 0; j < 4; ++j) { bg[j] = Bg[kk][tx * 4 + j]; bu[j] = Bu[kk][tx * 4 + j]; }
#pragma unroll
                for (int i = 0; i < 4; ++i)
#pragma unroll
                    for (int j = 0; j < 4; ++j) { cg[i][j] += a[i] * bg[j]; cu[i][j] += a[i] * bu[j]; }
            }
            __syncthreads();
        }
#pragma unroll
        for (int i = 0; i < 4; ++i) {
            int m = ty * 4 + i;
            if (m0 + m >= cnt) continue;
#pragma unroll
            for (int j = 0; j < 4; ++j) {
                float g = cg[i][j];
                float val = g / (1.f + expf(-g)) * cu[i][j];
                t_out[(size_t)(base + m0 + m) * IM + n0 + tx * 4 + j] = val;
            }
        }
        __syncthreads();
    }
}

// ---------------- expert down proj + weighted atomic combine ---------------
// grid: (H/BN, E)
__global__ __launch_bounds__(256)
void expert_down_kernel(const float* __restrict__ t_in, const float* __restrict__ wd_all,
                        const int* __restrict__ counts, const int* __restrict__ offs,
                        const int* __restrict__ tok_list, const float* __restrict__ pw,
                        float* __restrict__ moe) {
    const int e = blockIdx.y;
    const int cnt = counts[e];
    if (cnt == 0) return;
    const int base = offs[e];
    const float* wd = wd_all + (size_t)e * IM * H;
    const int n0 = blockIdx.x * BN;
    __shared__ float As[BK][BM + 4];
    __shared__ float Bs[BK][BN + 4];
    const int tid = threadIdx.x, tx = tid & 15, ty = tid >> 4;
    for (int m0 = 0; m0 < cnt; m0 += BM) {
        float c[4][4] = {};
        for (int k0 = 0; k0 < IM; k0 += BK) {
            for (int i = tid; i < BM * BK; i += 256) {
                int m = i / BK, kk = i % BK;
                As[kk][m] = (m0 + m < cnt) ? t_in[(size_t)(base + m0 + m) * IM + k0 + kk] : 0.f;
            }
            for (int i = tid; i < BK * BN; i += 256) {
                int kk = i / BN, n = i % BN;
                Bs[kk][n] = wd[(size_t)(k0 + kk) * H + n0 + n];
            }
            __syncthreads();
#pragma unroll
            for (int kk = 0; kk < BK; ++kk) {
                float a[4], b[4];
#pragma unroll
                for (int i = 0; i < 4; ++i) a[i] = As[kk][ty * 4 + i];
#pragma unroll
                for (int j = 0; j < 4; ++j) b[j] = Bs[kk][tx * 4 + j];
#pragma unroll
                for (int i = 0; i < 4; ++i)
#pragma unroll
                    for (int j = 0; j < 4; ++j) c[i][j] += a[i] * b[j];
            }
            __syncthreads();
        }
#pragma unroll
        for (int i = 0; i < 4; ++i) {
            int m = ty * 4 + i;
            if (m0 + m >= cnt) continue;
            int s = tok_list[base + m0 + m];
            float w = pw[base + m0 + m];
#pragma unroll
            for (int j = 0; j < 4; ++j)
                atomicAdd(&moe[(size_t)s * H + n0 + tx * 4 + j], w * c[i][j]);
        }
    }
}

// ---------------- final: out = moe + shared ----------------
__global__ __launch_bounds__(256)
void final_add_kernel(const float* __restrict__ a, const float* __restrict__ b,
                      float* __restrict__ o, size_t n) {
    size_t i = (size_t)blockIdx.x * 256 + threadIdx.x;
    if (i < n) o[i] = a[i] + b[i];
}

// ---------------- host launch ----------------
extern "C" void kernel_launch(void* const* d_in, const int* in_sizes, int n_in,
                              void* d_out, int out_size, void* d_ws, size_t ws_size,
                              hipStream_t stream) {
    const int*   positions = (const int*)  d_in[0];
    const float* hidden    = (const float*)d_in[1];
    const float* ln1_w     = (const float*)d_in[2];
    const float* ln2_w     = (const float*)d_in[3];
    const float* q_w       = (const float*)d_in[4];
    const float* q_b       = (const float*)d_in[5];
    const float* k_w       = (const float*)d_in[6];
    const float* k_b       = (const float*)d_in[7];
    const float* v_w       = (const float*)d_in[8];
    const float* v_b       = (const float*)d_in[9];
    const float* o_w       = (const float*)d_in[10];
    const float* router_w  = (const float*)d_in[11];
    const float* we_gate   = (const float*)d_in[12];
    const float* we_up     = (const float*)d_in[13];
    const float* we_down   = (const float*)d_in[14];
    const float* ws_gate   = (const float*)d_in[15];
    const float* ws_up     = (const float*)d_in[16];
    const float* ws_down   = (const float*)d_in[17];
    const float* wsg       = (const float*)d_in[18];
    float* out = (float*)d_out;

    const size_t SH  = (size_t)S * H;    // 2,097,152
    const size_t SIS = (size_t)S * IS;   // 5,767,168 (== 4096*IM exactly)

    float* f = (float*)d_ws;
    float* h1  = f; f += SH;     // also attention output
    float* qb  = f; f += SH;     // q; later moe accumulator
    float* kb  = f; f += SH;     // k; later shared-expert output
    float* vb  = f; f += SH;
    float* x2  = f; f += SH;
    float* h2  = f; f += SH;
    float* gb  = f; f += SIS;    // shared gate; then t_shared
    float* ub  = f; f += SIS;    // shared up; later expert intermediate t_e
    float* logits = f; f += (size_t)S * E;
    float* tkw    = f; f += (size_t)S * TOPK;
    float* pw     = f; f += (size_t)S * TOPK;
    int* ip       = (int*)f;
    int* tk_ids   = ip; ip += S * TOPK;
    int* counts   = ip; ip += E;
    int* offs     = ip; ip += E;
    int* fill     = ip; ip += E;
    int* tok_list = ip; ip += S * TOPK;

    float* attn_out = h1;
    float* moe      = qb;
    float* shared_o = kb;
    float* t_e      = ub;

    dim3 g2048(H / BN, S / BM);        // (32,16)
    dim3 gIS(IS / BN, S / BM);         // (88,16)

    // --- pre-attention ---
    rmsnorm_kernel<<<S, 256, 0, stream>>>(hidden, ln1_w, h1);
    gemm_f32<<<g2048, 256, 0, stream>>>(h1, q_w, q_b, nullptr, qb, S, NH * HD, H);
    gemm_f32<<<g2048, 256, 0, stream>>>(h1, k_w, k_b, nullptr, kb, S, NH * HD, H);
    gemm_f32<<<g2048, 256, 0, stream>>>(h1, v_w, v_b, nullptr, vb, S, NH * HD, H);
    rope_kernel<<<dim3(S, NH), 64, 0, stream>>>(qb, positions);
    rope_kernel<<<dim3(S, NH), 64, 0, stream>>>(kb, positions);
    attn_kernel<<<dim3(S, NH), 256, 0, stream>>>(qb, kb, vb, attn_out);
    // x2 = attn @ o_w + residual(hidden)
    gemm_f32<<<g2048, 256, 0, stream>>>(attn_out, o_w, nullptr, hidden, x2, S, H, H);
    rmsnorm_kernel<<<S, 256, 0, stream>>>(x2, ln2_w, h2);

    // --- shared expert ---
    gemm_f32<<<gIS, 256, 0, stream>>>(h2, ws_gate, nullptr, nullptr, gb, S, IS, H);
    gemm_f32<<<gIS, 256, 0, stream>>>(h2, ws_up,   nullptr, nullptr, ub, S, IS, H);
    silu_mul_kernel<<<(int)(SIS / 256), 256, 0, stream>>>(gb, ub, gb, SIS);
    gemm_f32<<<g2048, 256, 0, stream>>>(gb, ws_down, nullptr, nullptr, shared_o, S, H, IS);
    gate_scale_kernel<<<S, 256, 0, stream>>>(h2, wsg, shared_o);

    // --- router ---
    gemm_f32<<<dim3(1, S / BM), 256, 0, stream>>>(h2, router_w, nullptr, nullptr, logits, S, E, H);
    router_top4_kernel<<<S / 256, 256, 0, stream>>>(logits, tk_ids, tkw);
    hipMemsetAsync(counts, 0, sizeof(int) * 3 * E, stream);  // counts, offs, fill
    count_pairs_kernel<<<S / 256, 256, 0, stream>>>(tk_ids, counts);
    scan_offsets_kernel<<<1, 64, 0, stream>>>(counts, offs);
    place_pairs_kernel<<<S / 256, 256, 0, stream>>>(tk_ids, tkw, offs, fill, tok_list, pw);

    // --- experts (sparse, grouped) ---
    hipMemsetAsync(moe, 0, SH * sizeof(float), stream);
    expert_gateup_kernel<<<dim3(IM / BN, E), 256, 0, stream>>>(h2, we_gate, we_up,
                                                               counts, offs, tok_list, t_e);
    expert_down_kernel<<<dim3(H / BN, E), 256, 0, stream>>>(t_e, we_down, counts, offs,
                                                            tok_list, pw, moe);

    // --- out = moe + shared ---
    final_add_kernel<<<(int)(SH / 256), 256, 0, stream>>>(moe, shared_o, out, SH);
}